// Round 1
// baseline (16.459 us; speedup 1.0000x reference)
//
#include <hip/hip_runtime.h>

// StreamingSTFT with no spectral processing: irfft(rfft(x)) == x, so the
// entire analyze->synthesize->OLA scan collapses to
//   out[i][t] = chunk[i-3][t] * W[t]   (i >= 3; zero otherwise)
//   W[t]      = sum_{k=0}^{3} aw[t+64k] * sw[t+64k]
// Pure memory-bound shifted copy with per-column scale.

#define N_FFT      256
#define HOP        64
#define NUM_FRAMES 131072

__global__ __launch_bounds__(256) void
StreamingSTFT_56951266345124_kernel(const float* __restrict__ chunk,
                                    const float* __restrict__ aw,
                                    const float* __restrict__ sw,
                                    float* __restrict__ out) {
    const long long total4 = (long long)NUM_FRAMES * HOP / 4;   // 2,097,152 float4s
    const long long stride = (long long)gridDim.x * blockDim.x; // multiple of 16
    long long g0 = (long long)blockIdx.x * blockDim.x + threadIdx.x;
    if (g0 >= total4) return;

    // stride % 16 == 0 -> this thread's column t is loop-invariant; hoist W.
    const int t = (int)(g0 & 15) * 4;
    float w0 = 0.f, w1 = 0.f, w2 = 0.f, w3 = 0.f;
    #pragma unroll
    for (int k = 0; k < 4; ++k) {
        const int n = t + HOP * k;
        w0 += aw[n + 0] * sw[n + 0];
        w1 += aw[n + 1] * sw[n + 1];
        w2 += aw[n + 2] * sw[n + 2];
        w3 += aw[n + 3] * sw[n + 3];
    }

    for (long long g = g0; g < total4; g += stride) {
        const int i = (int)(g >> 4);   // frame index (16 float4 per frame)
        float4 r;
        if (i >= 3) {
            const float4 c = *reinterpret_cast<const float4*>(
                chunk + (long long)(i - 3) * HOP + t);
            r.x = c.x * w0;
            r.y = c.y * w1;
            r.z = c.z * w2;
            r.w = c.w * w3;
        } else {
            r = make_float4(0.f, 0.f, 0.f, 0.f);
        }
        *reinterpret_cast<float4*>(out + g * 4) = r;
    }
}

extern "C" void kernel_launch(void* const* d_in, const int* in_sizes, int n_in,
                              void* d_out, int out_size, void* d_ws, size_t ws_size,
                              hipStream_t stream) {
    const float* chunk = (const float*)d_in[0];
    const float* aw    = (const float*)d_in[1];
    const float* sw    = (const float*)d_in[2];
    float* out         = (float*)d_out;

    const int threads = 256;
    const int blocks  = 2048;  // grid-stride; 2048*256 = 524288 (multiple of 16)
    StreamingSTFT_56951266345124_kernel<<<blocks, threads, 0, stream>>>(chunk, aw, sw, out);
}

// Round 2
// 15.924 us; speedup vs baseline: 1.0336x; 1.0336x over previous
//
#include <hip/hip_runtime.h>

// StreamingSTFT with no spectral processing: irfft(rfft(x)) == x, so the whole
// analyze->synthesize->OLA scan collapses to
//   out[i][t] = chunk[i-3][t] * W[t]   (i >= 3; zero otherwise)
// where W[t] = sum_k aw[t+64k]*sw[t+64k]. The synthesis window sw is
// pad(sqrt_hann(64),(96,96)) -> nonzero only on [96,160), so exactly one k
// contributes: W[t] = aw[t+128]*sw[t+128] (t<32) else aw[t+64]*sw[t+64].
// In float4 units, out4[g] = chunk4[g-48] * W4[g & 15]  (g >= 48).
// Pure memory-bound shifted scaled copy: 32 MB read + 32 MB write.

#define HOP        64
#define NUM_FRAMES 131072

__global__ __launch_bounds__(256) void
StreamingSTFT_56951266345124_kernel(const float4* __restrict__ chunk4,
                                    const float* __restrict__ aw,
                                    const float* __restrict__ sw,
                                    float4* __restrict__ out4) {
    const int g0 = blockIdx.x * 256 + threadIdx.x;   // 0 .. 524287
    const int t  = (g0 & 15) * 4;                    // column in {0,4,...,60}; loop-invariant
    // exactly one window term is nonzero; columns t..t+3 never straddle t=32
    const int n  = t + ((t < 32) ? 128 : 64);
    const float4 a4 = *reinterpret_cast<const float4*>(aw + n);
    const float4 s4 = *reinterpret_cast<const float4*>(sw + n);
    const float4 w  = make_float4(a4.x * s4.x, a4.y * s4.y, a4.z * s4.z, a4.w * s4.w);

    #pragma unroll
    for (int it = 0; it < 4; ++it) {
        const int g = g0 + it * 524288;              // max 2,097,151: fits int
        float4 r;
        if (g >= 48) {                               // only 48 threads total take else
            const float4 c = chunk4[g - 48];
            r = make_float4(c.x * w.x, c.y * w.y, c.z * w.z, c.w * w.w);
        } else {
            r = make_float4(0.f, 0.f, 0.f, 0.f);
        }
        out4[g] = r;
    }
}

extern "C" void kernel_launch(void* const* d_in, const int* in_sizes, int n_in,
                              void* d_out, int out_size, void* d_ws, size_t ws_size,
                              hipStream_t stream) {
    const float* chunk = (const float*)d_in[0];
    const float* aw    = (const float*)d_in[1];
    const float* sw    = (const float*)d_in[2];
    float* out         = (float*)d_out;

    // 2048 blocks x 256 threads = 524288 threads; 4 float4 each = 2,097,152
    // float4 = full 131072x64 output. 8 blocks/CU -> full occupancy.
    StreamingSTFT_56951266345124_kernel<<<2048, 256, 0, stream>>>(
        (const float4*)chunk, aw, sw, (float4*)out);
}